// Round 5
// baseline (120.651 us; speedup 1.0000x reference)
//
#include <hip/hip_runtime.h>
#include <hip/hip_bf16.h>
#include <stdint.h>

#define B_    4
#define N_    8192
#define K_    32
#define CX    67      // 3 + C_IN
#define CMID  64
#define COUT  128

#define W1S   104     // W1 LDS row stride (elems): 52 words = 20 mod 32 -> conflict-free b128
#define W2S   72      // W2 / H row stride (elems): 36 words = 4 mod 32 -> conflict-free b128
#define TPG   4       // points per wave per WG
#define NWG   2048
#define GMAX  8191

#define W1E   (64 * W1S)              // 6656 elems
#define HB0   (W1E + 128 * W2S)       // 15872 elems
#define SMEME (HB0 + 4 * 32 * W2S)    // 25088 elems = 50176 B

typedef __bf16 bf16_t;
typedef bf16_t bf16x8 __attribute__((ext_vector_type(8)));
typedef float  f32x4  __attribute__((ext_vector_type(4)));

__device__ __forceinline__ uint32_t pack2bf(float a, float b) {
    union { bf16_t h[2]; uint32_t u; } x;
    x.h[0] = (bf16_t)a; x.h[1] = (bf16_t)b;
    return x.u;
}

template<bool DIRECT>
__global__ __launch_bounds__(256, 3)
void sa_main(const float* __restrict__ dp, const float* __restrict__ fj,
             const float* __restrict__ W1, const float* __restrict__ b1,
             const float* __restrict__ W2, const float* __restrict__ b2,
             float* __restrict__ dst)
{
    __shared__ bf16_t smem[SMEME];

    const int tid  = threadIdx.x;
    const int wave = tid >> 6;
    const int lane = tid & 63;
    const int lrow = lane & 15;   // MFMA row/col within 16-tile
    const int g    = lane >> 4;   // 16-lane group (fragment k-group)

    const size_t plane = (size_t)N_ * K_;
    const int bidx = blockIdx.x;
    const int b    = (bidx * TPG) >> 11;   // batch constant per WG (TPG | 2048)

    const float* dpb = dp + (size_t)b * 3  * plane;
    const float* fjb = fj + (size_t)b * 64 * plane;

    // per-lane channel-base pointers; chan = kc*32 + g*8 + e
    const float* baseA = (g == 0) ? dpb
                       : fjb + (ptrdiff_t)(8 * g - 3) * (ptrdiff_t)plane;   // kc=0, e=0..2
    const float* baseB = fjb + (ptrdiff_t)(8 * g - 3) * (ptrdiff_t)plane;   // kc=0, e=3..7
    const float* base1 = fjb + (size_t)(29 + 8 * g) * plane;                // kc=1, e=0..7
    const float* base2 = fjb + (size_t)61 * plane;                          // kc=2 (g==0, e<3)

    // landing registers: ct0 (cols lrow) and ct1 (cols 16+lrow), 19 channels each
    float la[19], lb[19];
    auto issue = [&](int G) {
        const int n = ((G & 2047) << 2) + wave;
        const size_t off = (size_t)n * K_ + lrow;
        const float* pA = baseA + off;
        const float* pB = baseB + off;
        const float* p1 = base1 + off;
        #pragma unroll
        for (int e = 0; e < 3; ++e) { la[e]   = pA[(size_t)e * plane]; lb[e]   = pA[(size_t)e * plane + 16]; }
        #pragma unroll
        for (int e = 3; e < 8; ++e) { la[e]   = pB[(size_t)e * plane]; lb[e]   = pB[(size_t)e * plane + 16]; }
        #pragma unroll
        for (int e = 0; e < 8; ++e) { la[8+e] = p1[(size_t)e * plane]; lb[8+e] = p1[(size_t)e * plane + 16]; }
        la[16] = la[17] = la[18] = 0.f;
        lb[16] = lb[17] = lb[18] = 0.f;
        if (g == 0) {   // exec-masked: pad channels never touch memory
            const float* p2 = base2 + off;
            #pragma unroll
            for (int e = 0; e < 3; ++e) { la[16+e] = p2[(size_t)e * plane]; lb[16+e] = p2[(size_t)e * plane + 16]; }
        }
    };

    // t=0 loads in flight across the whole weight prologue
    issue(bidx * TPG);

    // ---- prologue: weights -> LDS (bf16, zero-padded) ----
    for (int i = tid; i < W1E; i += 256) {
        int o = i / W1S, c = i - o * W1S;
        smem[i] = (c < CX) ? (bf16_t)W1[o * CX + c] : (bf16_t)0.f;
    }
    for (int i = tid; i < 128 * W2S; i += 256) {
        int o = i / W2S, c = i - o * W2S;
        smem[W1E + i] = (c < CMID) ? (bf16_t)W2[o * CMID + c] : (bf16_t)0.f;
    }
    __syncthreads();

    f32x4 b1f[4];
    #pragma unroll
    for (int rt = 0; rt < 4; ++rt) b1f[rt] = *(const f32x4*)(b1 + rt * 16 + g * 4);
    float b2f[8];
    #pragma unroll
    for (int ot = 0; ot < 8; ++ot) b2f[ot] = b2[ot * 16 + lrow];

    bf16_t* Hw = smem + HB0 + wave * 32 * W2S;
    const bf16_t* W2l = smem + W1E;

    #pragma unroll 1
    for (int t = 0; t < TPG; ++t) {
        const int G = bidx * TPG + t;
        const int n = ((G & 2047) << 2) + wave;

        // ---- cvt landing -> B-frags (frees landing regs) ----
        bf16x8 f0[3], f1[3];
        {
            union { uint32_t u[4]; bf16x8 v; } cv;
            cv.u[0] = pack2bf(la[0], la[1]);   cv.u[1] = pack2bf(la[2], la[3]);
            cv.u[2] = pack2bf(la[4], la[5]);   cv.u[3] = pack2bf(la[6], la[7]);   f0[0] = cv.v;
            cv.u[0] = pack2bf(la[8], la[9]);   cv.u[1] = pack2bf(la[10], la[11]);
            cv.u[2] = pack2bf(la[12], la[13]); cv.u[3] = pack2bf(la[14], la[15]); f0[1] = cv.v;
            cv.u[0] = pack2bf(la[16], la[17]); cv.u[1] = pack2bf(la[18], 0.f);
            cv.u[2] = 0;                       cv.u[3] = 0;                       f0[2] = cv.v;
            cv.u[0] = pack2bf(lb[0], lb[1]);   cv.u[1] = pack2bf(lb[2], lb[3]);
            cv.u[2] = pack2bf(lb[4], lb[5]);   cv.u[3] = pack2bf(lb[6], lb[7]);   f1[0] = cv.v;
            cv.u[0] = pack2bf(lb[8], lb[9]);   cv.u[1] = pack2bf(lb[10], lb[11]);
            cv.u[2] = pack2bf(lb[12], lb[13]); cv.u[3] = pack2bf(lb[14], lb[15]); f1[1] = cv.v;
            cv.u[0] = pack2bf(lb[16], lb[17]); cv.u[1] = pack2bf(lb[18], 0.f);
            cv.u[2] = 0;                       cv.u[3] = 0;                       f1[2] = cv.v;
        }
        // ---- reissue landing set for next point: hides under this point's compute ----
        { int Gn = G + 1; if (Gn > GMAX) Gn = GMAX; issue(Gn); }

        // ---- layer 1: acc = W1(A, from LDS) * X(B, from regs), both ct halves ----
        f32x4 acc0[4] = {}, acc1v[4] = {};
        __builtin_amdgcn_s_setprio(1);
        #pragma unroll
        for (int kc = 0; kc < 3; ++kc) {
            #pragma unroll
            for (int rt = 0; rt < 4; ++rt) {
                bf16x8 wf = *(const bf16x8*)&smem[(rt * 16 + lrow) * W1S + kc * 32 + g * 8];
                acc0[rt]  = __builtin_amdgcn_mfma_f32_16x16x32_bf16(wf, f0[kc], acc0[rt], 0, 0, 0);
                acc1v[rt] = __builtin_amdgcn_mfma_f32_16x16x32_bf16(wf, f1[kc], acc1v[rt], 0, 0, 0);
            }
        }
        __builtin_amdgcn_s_setprio(0);

        // ---- epilogue 1: bias+relu -> bf16 -> H (wave-private, both halves) ----
        #pragma unroll
        for (int rt = 0; rt < 4; ++rt) {
            float h0 = fmaxf(acc0[rt][0] + b1f[rt][0], 0.f);
            float h1 = fmaxf(acc0[rt][1] + b1f[rt][1], 0.f);
            float h2 = fmaxf(acc0[rt][2] + b1f[rt][2], 0.f);
            float h3 = fmaxf(acc0[rt][3] + b1f[rt][3], 0.f);
            *(uint2*)&Hw[lrow * W2S + rt * 16 + g * 4] =
                make_uint2(pack2bf(h0, h1), pack2bf(h2, h3));
            float j0 = fmaxf(acc1v[rt][0] + b1f[rt][0], 0.f);
            float j1 = fmaxf(acc1v[rt][1] + b1f[rt][1], 0.f);
            float j2 = fmaxf(acc1v[rt][2] + b1f[rt][2], 0.f);
            float j3 = fmaxf(acc1v[rt][3] + b1f[rt][3], 0.f);
            *(uint2*)&Hw[(16 + lrow) * W2S + rt * 16 + g * 4] =
                make_uint2(pack2bf(j0, j1), pack2bf(j2, j3));
        }

        // ---- layer 2: A = H (LDS), B = W2 (LDS); D rows = k-positions ----
        bf16x8 hb00 = *(const bf16x8*)&Hw[lrow * W2S + g * 8];
        bf16x8 hb01 = *(const bf16x8*)&Hw[lrow * W2S + 32 + g * 8];
        bf16x8 hb10 = *(const bf16x8*)&Hw[(16 + lrow) * W2S + g * 8];
        bf16x8 hb11 = *(const bf16x8*)&Hw[(16 + lrow) * W2S + 32 + g * 8];

        float macc[8];
        __builtin_amdgcn_s_setprio(1);
        #pragma unroll
        for (int bt = 0; bt < 2; ++bt) {
            f32x4 a20[4] = {}, a21[4] = {};
            #pragma unroll
            for (int o = 0; o < 4; ++o) {
                #pragma unroll
                for (int kc2 = 0; kc2 < 2; ++kc2) {
                    bf16x8 wf = *(const bf16x8*)&W2l[((bt * 4 + o) * 16 + lrow) * W2S + kc2 * 32 + g * 8];
                    if (kc2 == 0) {
                        a20[o] = __builtin_amdgcn_mfma_f32_16x16x32_bf16(hb00, wf, a20[o], 0, 0, 0);
                        a21[o] = __builtin_amdgcn_mfma_f32_16x16x32_bf16(hb10, wf, a21[o], 0, 0, 0);
                    } else {
                        a20[o] = __builtin_amdgcn_mfma_f32_16x16x32_bf16(hb01, wf, a20[o], 0, 0, 0);
                        a21[o] = __builtin_amdgcn_mfma_f32_16x16x32_bf16(hb11, wf, a21[o], 0, 0, 0);
                    }
                }
            }
            #pragma unroll
            for (int o = 0; o < 4; ++o) {
                float m0 = fmaxf(fmaxf(a20[o][0], a20[o][1]), fmaxf(a20[o][2], a20[o][3]));
                float m1 = fmaxf(fmaxf(a21[o][0], a21[o][1]), fmaxf(a21[o][2], a21[o][3]));
                macc[bt * 4 + o] = fmaxf(m0, m1);
            }
        }
        __builtin_amdgcn_s_setprio(0);

        // ---- cross-group pool (xor16 + xor32), bias, relu ----
        #pragma unroll
        for (int ot = 0; ot < 8; ++ot) {
            float vv = macc[ot];
            vv = fmaxf(vv, __shfl_xor(vv, 16, 64));
            vv = fmaxf(vv, __shfl_xor(vv, 32, 64));
            macc[ot] = fmaxf(vv + b2f[ot], 0.f);
        }
        float oa = (g == 0) ? macc[0] : (g == 1) ? macc[2] : (g == 2) ? macc[4] : macc[6];
        float ob = (g == 0) ? macc[1] : (g == 1) ? macc[3] : (g == 2) ? macc[5] : macc[7];
        const int ca = g * 32 + lrow;
        const int cb = g * 32 + 16 + lrow;
        if (DIRECT) {
            float* op = dst + (size_t)b * COUT * N_ + n;
            op[(size_t)ca * N_] = oa;
            op[(size_t)cb * N_] = ob;
        } else {
            float* wp = dst + ((size_t)(b * N_ + n)) * COUT;   // ws[b][n][c]
            wp[ca] = oa;
            wp[cb] = ob;
        }
    }
}

// ws[b][n][c] -> out[b][c][n], full lines on both sides
__global__ __launch_bounds__(256)
void sa_transpose(const float* __restrict__ ws, float* __restrict__ out)
{
    __shared__ float tile[32][136];
    const int t  = threadIdx.x;
    const int i  = blockIdx.x;         // 0..1023
    const int b  = i >> 8;
    const int n0 = (i & 255) << 5;

    const float* rp = ws + ((size_t)(b * N_ + n0)) * COUT;
    #pragma unroll
    for (int r = 0; r < 4; ++r) {
        int flat = (r * 256 + t) * 4;
        int nl = flat >> 7, c = flat & 127;
        float4 v = *(const float4*)(rp + (size_t)nl * COUT + c);
        *(float4*)&tile[nl][c] = v;
    }
    __syncthreads();
    float* op = out + (size_t)b * COUT * N_ + n0;
    const int nl4 = (t & 7) << 2;
    #pragma unroll
    for (int r2 = 0; r2 < 4; ++r2) {
        int c = r2 * 32 + (t >> 3);
        float4 o4;
        o4.x = tile[nl4 + 0][c];
        o4.y = tile[nl4 + 1][c];
        o4.z = tile[nl4 + 2][c];
        o4.w = tile[nl4 + 3][c];
        *(float4*)(op + (size_t)c * N_ + nl4) = o4;
    }
}

extern "C" void kernel_launch(void* const* d_in, const int* in_sizes, int n_in,
                              void* d_out, int out_size, void* d_ws, size_t ws_size,
                              hipStream_t stream) {
    // inputs: 0=p (unused), 1=f (unused), 2=dp, 3=fj, 4=W1, 5=b1, 6=W2, 7=b2
    const float* dp = (const float*)d_in[2];
    const float* fj = (const float*)d_in[3];
    const float* W1 = (const float*)d_in[4];
    const float* b1 = (const float*)d_in[5];
    const float* W2 = (const float*)d_in[6];
    const float* b2 = (const float*)d_in[7];
    float* out = (float*)d_out;

    const size_t ws_need = (size_t)B_ * N_ * COUT * sizeof(float);
    if (ws_size >= ws_need) {
        float* ws = (float*)d_ws;
        hipLaunchKernelGGL((sa_main<false>), dim3(NWG), dim3(256), 0, stream,
                           dp, fj, W1, b1, W2, b2, ws);
        hipLaunchKernelGGL(sa_transpose, dim3(1024), dim3(256), 0, stream, ws, out);
    } else {
        hipLaunchKernelGGL((sa_main<true>), dim3(NWG), dim3(256), 0, stream,
                           dp, fj, W1, b1, W2, b2, out);
    }
}